// Round 4
// baseline (706.513 us; speedup 1.0000x reference)
//
#include <hip/hip_runtime.h>

#define BT 16384
#define DK 4096
#define NE 64
#define BM 64                 // rows per block (= rows per wave tile)
#define NW 8                  // waves per block, split-K by 8
#define KW (DK / NW)          // 512 k per wave
#define KC 16                 // k floats per step (4 quads)
#define NS (KW / KC)          // 32 steps
#define NPROBS (BT * NE)
#define NIDX (NPROBS)
#define NWTS (NPROBS + BT * 2)

// One wave computes the FULL 64x64 (rows x experts) tile for its 512-k slice:
// lane = rlg*8+elg; per-lane 8 rows x 8 experts = 64 acc. LDS bytes/lane-FMA
// = 1.0 (vs 4.0 in round 2) -> LDS roofline 55us ~= fp32 FMA floor 54.6us.
// Each wave owns a private 16KB double-buffered LDS region -> NO barriers in
// the main loop; waves are independent self-paced pipelines.

__global__ __launch_bounds__(512, 2) void token_router(
    const float* __restrict__ x, const float* __restrict__ W,
    float* __restrict__ out)
{
    __shared__ float4 sh[NW * 1024];   // 128 KB: per wave [2 buf][X 256 f4 | W 256 f4]

    const int tid  = threadIdx.x;
    const int wv   = tid >> 6;
    const int lane = tid & 63;
    const int rlg  = lane >> 3;        // row-oct selector
    const int elg  = lane & 7;         // expert-oct selector
    const long rowbase = (long)blockIdx.x * BM;

    // staging: thread stages slots {j*64+lane}: row j*16+(lane>>2), quad lane&3
    const int srow = lane >> 2;
    const int sq   = lane & 3;
    const float* gx[4];
    const float* gw[4];
#pragma unroll
    for (int j = 0; j < 4; ++j) {
        gx[j] = x + (rowbase + j * 16 + srow) * (long)DK + wv * KW + sq * 4;
        gw[j] = W + (long)(j * 16 + srow) * DK + wv * KW + sq * 4;
    }

    float4* const reg  = sh + wv * 1024;        // this wave's private region
    float4* const stx  = reg + lane;            // + buf*512 + j*64
    float4* const stwp = reg + 256 + lane;
    const float4* const xrb = reg + rlg * 32;   // + buf*512 + i*4 + q
    const float4* const wrb = reg + 256 + elg * 32;

    float acc[8][8];
#pragma unroll
    for (int i = 0; i < 8; ++i)
#pragma unroll
        for (int j = 0; j < 8; ++j) acc[i][j] = 0.f;

    // prologue: stage step 0 into buf 0 (intra-wave deps via waitcnt only)
#pragma unroll
    for (int j = 0; j < 4; ++j) {
        stx [j * 64] = *(const float4*)(gx[j]);
        stwp[j * 64] = *(const float4*)(gw[j]);
    }

    for (int c = 0; c < NS; ++c) {
        const int buf = (c & 1) * 512;
        float4 pa[4], pb[4];
        if (c + 1 < NS) {                       // issue next-step globals early
#pragma unroll
            for (int j = 0; j < 4; ++j) {
                pa[j] = *(const float4*)(gx[j] + (c + 1) * KC);
                pb[j] = *(const float4*)(gw[j] + (c + 1) * KC);
            }
        }
#pragma unroll
        for (int q = 0; q < 4; ++q) {
            float4 xq[8], wq[8];
#pragma unroll
            for (int i = 0; i < 8; ++i) xq[i] = xrb[buf + i * 4 + q];
#pragma unroll
            for (int j = 0; j < 8; ++j) wq[j] = wrb[buf + j * 4 + q];
#pragma unroll
            for (int i = 0; i < 8; ++i)
#pragma unroll
                for (int j = 0; j < 8; ++j) {
                    acc[i][j] = fmaf(xq[i].x, wq[j].x, acc[i][j]);
                    acc[i][j] = fmaf(xq[i].y, wq[j].y, acc[i][j]);
                    acc[i][j] = fmaf(xq[i].z, wq[j].z, acc[i][j]);
                    acc[i][j] = fmaf(xq[i].w, wq[j].w, acc[i][j]);
                }
        }
        if (c + 1 < NS) {                       // write-late into other buffer
            const int nbuf = ((c + 1) & 1) * 512;
#pragma unroll
            for (int j = 0; j < 4; ++j) {
                stx [nbuf + j * 64] = pa[j];
                stwp[nbuf + j * 64] = pb[j];
            }
        }
    }

    // ---- split-K tree reduction (fixed order -> deterministic fp32) ----
    // dump layout per region: [t*64 + lane] float4, t=0..15 -> conflict-free
    auto dump = [&](float4* r) {
#pragma unroll
        for (int i = 0; i < 8; ++i) {
            r[(i * 2 + 0) * 64 + lane] = make_float4(acc[i][0], acc[i][1], acc[i][2], acc[i][3]);
            r[(i * 2 + 1) * 64 + lane] = make_float4(acc[i][4], acc[i][5], acc[i][6], acc[i][7]);
        }
    };
    auto addin = [&](const float4* r) {
#pragma unroll
        for (int i = 0; i < 8; ++i) {
            float4 a = r[(i * 2 + 0) * 64 + lane];
            float4 b = r[(i * 2 + 1) * 64 + lane];
            acc[i][0] += a.x; acc[i][1] += a.y; acc[i][2] += a.z; acc[i][3] += a.w;
            acc[i][4] += b.x; acc[i][5] += b.y; acc[i][6] += b.z; acc[i][7] += b.w;
        }
    };
    __syncthreads();
    if (wv >= 4) dump(sh + wv * 1024);
    __syncthreads();
    if (wv < 4) addin(sh + (wv + 4) * 1024);
    __syncthreads();
    if (wv == 2 || wv == 3) dump(sh + wv * 1024);
    __syncthreads();
    if (wv < 2) addin(sh + (wv + 2) * 1024);
    __syncthreads();
    if (wv == 1) dump(sh + 1024);
    __syncthreads();

    if (wv == 0) {
        addin(sh + 1024);
        // per-row epilogue; row's 64 experts live across the 8 elg lanes
        for (int i = 0; i < 8; ++i) {
            float l[8];
#pragma unroll
            for (int j = 0; j < 8; ++j) l[j] = acc[i][j];
            float m = l[0];
#pragma unroll
            for (int j = 1; j < 8; ++j) m = fmaxf(m, l[j]);
            m = fmaxf(m, __shfl_xor(m, 1));
            m = fmaxf(m, __shfl_xor(m, 2));
            m = fmaxf(m, __shfl_xor(m, 4));
            float s = 0.f;
#pragma unroll
            for (int j = 0; j < 8; ++j) s += __expf(l[j] - m);
            s += __shfl_xor(s, 1);
            s += __shfl_xor(s, 2);
            s += __shfl_xor(s, 4);
            const float inv = 1.f / s;
            float p[8];
#pragma unroll
            for (int j = 0; j < 8; ++j) p[j] = __expf(l[j] - m) * inv;

            // local top-2 (ascending idx + strict > == stable lower-index ties)
            float v1 = p[0], v2 = -1.f;
            int   i1 = elg * 8, i2 = elg * 8;
#pragma unroll
            for (int j = 1; j < 8; ++j) {
                const int idx = elg * 8 + j;
                if (p[j] > v1)      { v2 = v1; i2 = i1; v1 = p[j]; i1 = idx; }
                else if (p[j] > v2) { v2 = p[j]; i2 = idx; }
            }
            // butterfly merge across elg lanes, ties -> lower index
#pragma unroll
            for (int ms = 1; ms < 8; ms <<= 1) {
                float b1 = __shfl_xor(v1, ms);
                float b2 = __shfl_xor(v2, ms);
                int  bi1 = __shfl_xor(i1, ms);
                int  bi2 = __shfl_xor(i2, ms);
                float n1, n2; int ni1, ni2;
                const bool btop = (b1 > v1) || (b1 == v1 && bi1 < i1);
                if (btop) {
                    n1 = b1; ni1 = bi1;
                    const bool asec = (v1 > b2) || (v1 == b2 && i1 < bi2);
                    n2 = asec ? v1 : b2; ni2 = asec ? i1 : bi2;
                } else {
                    n1 = v1; ni1 = i1;
                    const bool bsec = (b1 > v2) || (b1 == v2 && bi1 < i2);
                    n2 = bsec ? b1 : v2; ni2 = bsec ? bi1 : i2;
                }
                v1 = n1; i1 = ni1; v2 = n2; i2 = ni2;
            }

            const long grow = rowbase + rlg * 8 + i;
            *reinterpret_cast<float4*>(&out[grow * (long)NE + elg * 8]) =
                make_float4(p[0], p[1], p[2], p[3]);
            *reinterpret_cast<float4*>(&out[grow * (long)NE + elg * 8 + 4]) =
                make_float4(p[4], p[5], p[6], p[7]);
            if (elg == 0) {
                out[NIDX + grow * 2 + 0] = (float)i1;
                out[NIDX + grow * 2 + 1] = (float)i2;
                const float dn = v1 + v2 + 1e-9f;
                out[NWTS + grow * 2 + 0] = v1 / dn;
                out[NWTS + grow * 2 + 1] = v2 / dn;
            }
        }
    }
}

extern "C" void kernel_launch(void* const* d_in, const int* in_sizes, int n_in,
                              void* d_out, int out_size, void* d_ws, size_t ws_size,
                              hipStream_t stream) {
    const float* x = (const float*)d_in[0];
    const float* W = (const float*)d_in[1];
    float* out = (float*)d_out;
    dim3 grid(BT / BM);   // 256 blocks, 1 per CU
    dim3 block(512);      // 8 waves
    token_router<<<grid, block, 0, stream>>>(x, W, out);
}

// Round 5
// 485.827 us; speedup vs baseline: 1.4542x; 1.4542x over previous
//
#include <hip/hip_runtime.h>

#define BT 16384
#define DK 4096
#define NE 64
#define BM 64                 // rows per block (= rows per wave tile)
#define NW 8                  // waves per block, split-K by 8
#define KW (DK / NW)          // 512 k per wave
#define KC 16                 // k floats per step (4 quads)
#define NS (KW / KC)          // 32 steps
#define NPROBS (BT * NE)
#define NIDX (NPROBS)
#define NWTS (NPROBS + BT * 2)

// One wave = full 64x64 (rows x experts) tile over its 512-k slice.
// lane: rlg=lane>>3 picks row-oct, elg=lane&7 picks expert-oct; 8x8 acc/lane.
// LDS layout per wave region (1024 float4): [buf][X 256 | W 256]; slot of
// (row r, quad q) = r*4+q (X), (expert e, quad q) = e*4+q (W). Reads use a
// per-lane ROTATED quad order t^rot (rot=(elg^rlg)&3), identical for X and W
// so k stays matched; this makes X reads pure broadcasts and W reads <=2-way
// bank aliased (free). No barriers in the main loop: wave-private regions.

__global__ __launch_bounds__(512, 1) void token_router(
    const float* __restrict__ x, const float* __restrict__ W,
    float* __restrict__ out)
{
    __shared__ float4 sh[NW * 1024];   // 128 KB

    const int tid  = threadIdx.x;
    const int wv   = tid >> 6;
    const int lane = tid & 63;
    const int rlg  = lane >> 3;
    const int elg  = lane & 7;
    const int rot  = (elg ^ rlg) & 3;
    const long rowbase = (long)blockIdx.x * BM;

    // staging: thread stages slot j*64+lane = (row j*16+(lane>>2))*4 + (lane&3)
    const int srow = lane >> 2;
    const int sq   = lane & 3;
    const float* gx[4];
    const float* gw[4];
#pragma unroll
    for (int j = 0; j < 4; ++j) {
        gx[j] = x + (rowbase + j * 16 + srow) * (long)DK + wv * KW + sq * 4;
        gw[j] = W + (long)(j * 16 + srow) * DK + wv * KW + sq * 4;
    }

    float4* const reg = sh + wv * 1024;     // this wave's private region
    float4* const stx = reg + lane;         // + buf + j*64
    float4* const stw = reg + 256 + lane;
    const float4* xt[4];
    const float4* wt[4];
#pragma unroll
    for (int t = 0; t < 4; ++t) {
        xt[t] = reg + rlg * 32 + (t ^ rot);          // + buf + i*4
        wt[t] = reg + 256 + elg * 32 + (t ^ rot);    // + buf + j*4
    }

    float acc[8][8];
#pragma unroll
    for (int i = 0; i < 8; ++i)
#pragma unroll
        for (int j = 0; j < 8; ++j) acc[i][j] = 0.f;

    // prologue: stage step 0 into buf 0
#pragma unroll
    for (int j = 0; j < 4; ++j) {
        stx[j * 64] = *(const float4*)(gx[j]);
        stw[j * 64] = *(const float4*)(gw[j]);
    }

#define STEP(c, BUF, NBUF) do {                                               \
    float4 pa[4], pb[4];                                                      \
    const bool pf = ((c) + 1 < NS);                                           \
    if (pf) {                                                                 \
        _Pragma("unroll") for (int j = 0; j < 4; ++j) {                       \
            pa[j] = *(const float4*)(gx[j] + ((c) + 1) * KC);                 \
            pb[j] = *(const float4*)(gw[j] + ((c) + 1) * KC);                 \
        }                                                                     \
    }                                                                         \
    _Pragma("unroll") for (int t = 0; t < 4; ++t) {                           \
        float4 xq[8], wq[8];                                                  \
        _Pragma("unroll") for (int i = 0; i < 8; ++i) xq[i] = xt[t][(BUF) + i * 4]; \
        _Pragma("unroll") for (int j = 0; j < 8; ++j) wq[j] = wt[t][(BUF) + j * 4]; \
        _Pragma("unroll") for (int i = 0; i < 8; ++i)                         \
            _Pragma("unroll") for (int j = 0; j < 8; ++j) {                   \
                acc[i][j] = fmaf(xq[i].x, wq[j].x, acc[i][j]);                \
                acc[i][j] = fmaf(xq[i].y, wq[j].y, acc[i][j]);                \
                acc[i][j] = fmaf(xq[i].z, wq[j].z, acc[i][j]);                \
                acc[i][j] = fmaf(xq[i].w, wq[j].w, acc[i][j]);                \
            }                                                                 \
    }                                                                         \
    if (pf) {                                                                 \
        _Pragma("unroll") for (int j = 0; j < 4; ++j) {                       \
            stx[(NBUF) + j * 64] = pa[j];                                     \
            stw[(NBUF) + j * 64] = pb[j];                                     \
        }                                                                     \
    }                                                                         \
} while (0)

    for (int c = 0; c < NS; c += 2) {
        STEP(c, 0, 512);
        STEP(c + 1, 512, 0);
    }
#undef STEP

    // ---- split-K tree reduction (fixed order -> deterministic fp32) ----
    auto dump = [&](float4* r) {
#pragma unroll
        for (int i = 0; i < 8; ++i) {
            r[(i * 2 + 0) * 64 + lane] = make_float4(acc[i][0], acc[i][1], acc[i][2], acc[i][3]);
            r[(i * 2 + 1) * 64 + lane] = make_float4(acc[i][4], acc[i][5], acc[i][6], acc[i][7]);
        }
    };
    auto addin = [&](const float4* r) {
#pragma unroll
        for (int i = 0; i < 8; ++i) {
            float4 a = r[(i * 2 + 0) * 64 + lane];
            float4 b = r[(i * 2 + 1) * 64 + lane];
            acc[i][0] += a.x; acc[i][1] += a.y; acc[i][2] += a.z; acc[i][3] += a.w;
            acc[i][4] += b.x; acc[i][5] += b.y; acc[i][6] += b.z; acc[i][7] += b.w;
        }
    };
    __syncthreads();
    if (wv >= 4) dump(sh + wv * 1024);
    __syncthreads();
    if (wv < 4) addin(sh + (wv + 4) * 1024);
    __syncthreads();
    if (wv == 2 || wv == 3) dump(sh + wv * 1024);
    __syncthreads();
    if (wv < 2) addin(sh + (wv + 2) * 1024);
    __syncthreads();
    if (wv == 1) dump(sh + 1024);
    __syncthreads();

    if (wv == 0) {
        addin(sh + 1024);
        // per-row epilogue; row's 64 experts live across the 8 elg lanes
        for (int i = 0; i < 8; ++i) {
            float l[8];
#pragma unroll
            for (int j = 0; j < 8; ++j) l[j] = acc[i][j];
            float m = l[0];
#pragma unroll
            for (int j = 1; j < 8; ++j) m = fmaxf(m, l[j]);
            m = fmaxf(m, __shfl_xor(m, 1));
            m = fmaxf(m, __shfl_xor(m, 2));
            m = fmaxf(m, __shfl_xor(m, 4));
            float s = 0.f;
#pragma unroll
            for (int j = 0; j < 8; ++j) s += __expf(l[j] - m);
            s += __shfl_xor(s, 1);
            s += __shfl_xor(s, 2);
            s += __shfl_xor(s, 4);
            const float inv = 1.f / s;
            float p[8];
#pragma unroll
            for (int j = 0; j < 8; ++j) p[j] = __expf(l[j] - m) * inv;

            // local top-2 (ascending idx + strict > == stable lower-index ties)
            float v1 = p[0], v2 = -1.f;
            int   i1 = elg * 8, i2 = elg * 8;
#pragma unroll
            for (int j = 1; j < 8; ++j) {
                const int idx = elg * 8 + j;
                if (p[j] > v1)      { v2 = v1; i2 = i1; v1 = p[j]; i1 = idx; }
                else if (p[j] > v2) { v2 = p[j]; i2 = idx; }
            }
            // butterfly merge across elg lanes, ties -> lower index
#pragma unroll
            for (int ms = 1; ms < 8; ms <<= 1) {
                float b1 = __shfl_xor(v1, ms);
                float b2 = __shfl_xor(v2, ms);
                int  bi1 = __shfl_xor(i1, ms);
                int  bi2 = __shfl_xor(i2, ms);
                float n1, n2; int ni1, ni2;
                const bool btop = (b1 > v1) || (b1 == v1 && bi1 < i1);
                if (btop) {
                    n1 = b1; ni1 = bi1;
                    const bool asec = (v1 > b2) || (v1 == b2 && i1 < bi2);
                    n2 = asec ? v1 : b2; ni2 = asec ? i1 : bi2;
                } else {
                    n1 = v1; ni1 = i1;
                    const bool bsec = (b1 > v2) || (b1 == v2 && bi1 < i2);
                    n2 = bsec ? b1 : v2; ni2 = bsec ? bi1 : i2;
                }
                v1 = n1; i1 = ni1; v2 = n2; i2 = ni2;
            }

            const long grow = rowbase + rlg * 8 + i;
            *reinterpret_cast<float4*>(&out[grow * (long)NE + elg * 8]) =
                make_float4(p[0], p[1], p[2], p[3]);
            *reinterpret_cast<float4*>(&out[grow * (long)NE + elg * 8 + 4]) =
                make_float4(p[4], p[5], p[6], p[7]);
            if (elg == 0) {
                out[NIDX + grow * 2 + 0] = (float)i1;
                out[NIDX + grow * 2 + 1] = (float)i2;
                const float dn = v1 + v2 + 1e-9f;
                out[NWTS + grow * 2 + 0] = v1 / dn;
                out[NWTS + grow * 2 + 1] = v2 / dn;
            }
        }
    }
}

extern "C" void kernel_launch(void* const* d_in, const int* in_sizes, int n_in,
                              void* d_out, int out_size, void* d_ws, size_t ws_size,
                              hipStream_t stream) {
    const float* x = (const float*)d_in[0];
    const float* W = (const float*)d_in[1];
    float* out = (float*)d_out;
    dim3 grid(BT / BM);   // 256 blocks, 1 per CU
    dim3 block(512);      // 8 waves
    token_router<<<grid, block, 0, stream>>>(x, W, out);
}